// Round 5
// baseline (403.804 us; speedup 1.0000x reference)
//
#include <hip/hip_runtime.h>
#include <math.h>

namespace {

typedef float f32x4 __attribute__((ext_vector_type(4)));
typedef float f32x16 __attribute__((ext_vector_type(16)));
typedef short bf16x8 __attribute__((ext_vector_type(8)));
typedef unsigned short ushort_t;

constexpr int B  = 1024;
constexpr int M  = 65536;
constexpr int D  = 384;
constexpr int H  = 384;
constexpr int KK = 5;
constexpr int NC = 128;         // chunks over M
constexpr int CHUNK = M / NC;   // 512 mems per chunk
constexpr float FEPS = 1e-8f;

__device__ __forceinline__ ushort_t f2bf(float x) {
  unsigned int u = __float_as_uint(x);
  unsigned int r = (u + 0x7FFFu + ((u >> 16) & 1u)) >> 16;   // RNE
  return (ushort_t)r;
}
__device__ __forceinline__ float bf2f(ushort_t h) {
  return __uint_as_float(((unsigned int)h) << 16);
}

__device__ __forceinline__ void async16(const ushort_t* g, ushort_t* l) {
  __builtin_amdgcn_global_load_lds(
      (const __attribute__((address_space(1))) unsigned int*)g,
      (__attribute__((address_space(3))) unsigned int*)l, 16, 0, 0);
}

__device__ __forceinline__ void insert3b(unsigned int* k, unsigned int v) {
  unsigned int t0 = min(k[0], v); k[0] = max(k[0], v);
  unsigned int t1 = min(k[1], t0); k[1] = max(k[1], t0);
  k[2] = max(k[2], t1);
}
__device__ __forceinline__ void insert5b(unsigned int* k, unsigned int v) {
  unsigned int t0 = min(k[0], v); k[0] = max(k[0], v);
  unsigned int t1 = min(k[1], t0); k[1] = max(k[1], t0);
  unsigned int t2 = min(k[2], t1); k[2] = max(k[2], t1);
  unsigned int t3 = min(k[3], t2); k[3] = max(k[3], t2);
  k[4] = max(k[4], t3);
}

// swizzled per-lane global k-offset for staging: LDS granule (lane&3) of row
// (lane>>2) holds logical granule (lane&3) ^ ((row>>1)&3).  [bank-conflict fix]
__device__ __forceinline__ int swz_koff(int lane) {
  return (((lane & 3) ^ ((lane >> 3) & 3)) * 8);
}

// device-scope grid barrier (96 co-resident blocks; monotone targets, no reset)
__device__ __forceinline__ void grid_barrier(unsigned int* bar, unsigned int target) {
  __threadfence();                 // agent-scope: my stores ordered
  __syncthreads();                 // block quiesce
  if (threadIdx.x == 0) {
    __hip_atomic_fetch_add(bar, 1u, __ATOMIC_ACQ_REL, __HIP_MEMORY_SCOPE_AGENT);
    while (__hip_atomic_load(bar, __ATOMIC_ACQUIRE, __HIP_MEMORY_SCOPE_AGENT) < target) {
      __builtin_amdgcn_s_sleep(8);
    }
  }
  __syncthreads();
  __threadfence();                 // acquire side for all threads
}

// ======= prep: mem hi-split+stats | q norm-hi | weight hi/lo splits =========
__global__ __launch_bounds__(256) void k_prep(
    const float* __restrict__ q, const float* __restrict__ mem,
    const float* __restrict__ coords, const float* __restrict__ sw,
    const float* __restrict__ W_ih, const float* __restrict__ W_hh,
    const float* __restrict__ W_g,
    ushort_t* __restrict__ qh, ushort_t* __restrict__ mh,
    float2* __restrict__ f2a, float2* __restrict__ f2b,
    ushort_t* __restrict__ wihh, ushort_t* __restrict__ wihl,
    ushort_t* __restrict__ whhh, ushort_t* __restrict__ whhl,
    ushort_t* __restrict__ wgh, ushort_t* __restrict__ wgl,
    unsigned int* __restrict__ bar) {
  int wv = threadIdx.x >> 6, lane = threadIdx.x & 63;
  int bid = blockIdx.x;
  if (bid == 0 && threadIdx.x == 0) *bar = 0u;   // reset RNN grid-barrier counter
  if (bid < M/4) {
    int r = bid*4 + wv;
    float cx = 0.f, cy = 0.f;
    for (int i = lane; i < H; i += 64) { cx += sw[2*i]; cy += sw[2*i+1]; }
#pragma unroll
    for (int o = 32; o > 0; o >>= 1) { cx += __shfl_xor(cx, o); cy += __shfl_xor(cy, o); }
    cx *= (1.0f/384.0f); cy *= (1.0f/384.0f);
    float2 x[3]; float s = 0.f;
#pragma unroll
    for (int k = 0; k < 3; ++k) {
      x[k] = ((const float2*)(mem + (size_t)r*D))[lane + 64*k];
      s += x[k].x*x[k].x + x[k].y*x[k].y;
    }
#pragma unroll
    for (int o = 32; o > 0; o >>= 1) s += __shfl_xor(s, o);
#pragma unroll
    for (int k = 0; k < 3; ++k) {
      ushort2 hh; hh.x = f2bf(x[k].x); hh.y = f2bf(x[k].y);
      ((ushort2*)(mh + (size_t)r*D))[lane + 64*k] = hh;
    }
    if (lane == 0) {
      float mn = sqrtf(s);
      float dx = coords[2*r] - cx, dy = coords[2*r+1] - cy;
      float act = 1.0f / (1.0f + sqrtf(dx*dx + dy*dy));
      f2a[r] = make_float2(1.0f / mn, act + 2.0f);
      f2b[r] = make_float2(mn, act);
    }
  } else if (bid < M/4 + B/4) {
    int r = (bid - M/4)*4 + wv;
    float2 x[3]; float s = 0.f;
#pragma unroll
    for (int k = 0; k < 3; ++k) {
      x[k] = ((const float2*)(q + (size_t)r*D))[lane + 64*k];
      s += x[k].x*x[k].x + x[k].y*x[k].y;
    }
#pragma unroll
    for (int o = 32; o > 0; o >>= 1) s += __shfl_xor(s, o);
    float inv = 1.0f / sqrtf(s);
#pragma unroll
    for (int k = 0; k < 3; ++k) {
      ushort2 nn; nn.x = f2bf(x[k].x * inv); nn.y = f2bf(x[k].y * inv);
      ((ushort2*)(qh + (size_t)r*D))[lane + 64*k] = nn;
    }
  } else {
    int r = (bid - M/4 - B/4)*4 + wv;   // 0..1151
    const float* src; ushort_t* dh; ushort_t* dl;
    if (r < 384)      { src = W_ih + (size_t)r*D;       dh = wihh + (size_t)r*D;       dl = wihl + (size_t)r*D; }
    else if (r < 768) { src = W_hh + (size_t)(r-384)*D; dh = whhh + (size_t)(r-384)*D; dl = whhl + (size_t)(r-384)*D; }
    else              { src = W_g  + (size_t)(r-768)*D; dh = wgh  + (size_t)(r-768)*D; dl = wgl  + (size_t)(r-768)*D; }
#pragma unroll
    for (int k = 0; k < 3; ++k) {
      float2 v = ((const float2*)src)[lane + 64*k];
      ushort_t h0 = f2bf(v.x), h1 = f2bf(v.y);
      ushort2 hh; hh.x = h0; hh.y = h1;
      ushort2 ll; ll.x = f2bf(v.x - bf2f(h0)); ll.y = f2bf(v.y - bf2f(h1));
      ((ushort2*)dh)[lane + 64*k] = hh;
      ((ushort2*)dl)[lane + 64*k] = ll;
    }
  }
}

// ====== sim: 1-term mh x qh 32x32x16 MFMA, BK=64, double-buffered 2-phase ===
// 1D grid 1024; XCD-aware decode: the 8 q-tiles sharing chunk nc are
// consecutive on XCD nc%8 -> chunk read from HBM once, L2-hit 7x.
// T3-minimum schedule: issue STAGE(buf^1, step+1) BEFORE compute(buf), then
// one __syncthreads (vmcnt0 drain) per step AFTER compute -> load latency
// hides under the MFMA phase; barriers halved vs stage/drain/compute.
__global__ __launch_bounds__(256, 2) void k_sim(
    const ushort_t* __restrict__ qh,
    const ushort_t* __restrict__ mh,
    const float2* __restrict__ f2a, unsigned int* __restrict__ keybuf) {
  __shared__ __align__(16) ushort_t sQh[2*8192];   // [buf][kb*4096+slot*512+lane*8]
  __shared__ __align__(16) ushort_t sMh[2*8192];
  __shared__ __align__(16) float2 sF[CHUNK];   // per-chunk (1/mn, act+2)

  const int tid = threadIdx.x, lane = tid & 63, wave = tid >> 6;
  const int wr = wave >> 1, wc = wave & 1;
  const int l31 = lane & 31, half = lane >> 5;
  const int flat = blockIdx.x;
  const int k8 = flat & 7, qb = (flat >> 3) & 7, mgrp = flat >> 6;
  const int nc = (mgrp << 3) | k8;
  const int rowoff = lane >> 2, koff = swz_koff(lane);
  const int gsw = (l31 >> 1) & 3;          // read-side swizzle
  const size_t qrow0 = (size_t)qb * 128;

  // stage chunk stats once (coalesced): 256 x float4 = 512 float2
  ((float4*)sF)[tid] = ((const float4*)(f2a + (size_t)nc * CHUNK))[tid];

  // per-wave slot decode for staging (same addressing as before)
  auto stage = [&](int buf, int mt, int k6) {
    const size_t mrow0 = (size_t)nc * CHUNK + (size_t)mt * 128;
    const int kt = k6 * 64;
#pragma unroll
    for (int n = 0; n < 8; ++n) {
      int f = wave*8 + n;
      int arr = f >> 4, sub = f & 15, kb = sub >> 3, slot = sub & 7;
      const ushort_t* src = arr == 0 ? qh : mh;
      ushort_t* dst = (arr == 0 ? sQh : sMh) + buf*8192;
      size_t rowb = arr == 0 ? qrow0 : mrow0;
      async16(src + (rowb + slot*16 + rowoff)*D + kt + kb*32 + koff,
              dst + kb*4096 + slot*512 + lane*8);
    }
  };

  unsigned int keys[2][3];
#pragma unroll
  for (int j = 0; j < 2; ++j) { keys[j][0] = 0; keys[j][1] = 0; keys[j][2] = 0; }

  // prologue: stage (mt=0,k6=0) into buf 0, drain
  stage(0, 0, 0);
  __syncthreads();

  int cur = 0;
  f32x16 acc[2][2];

  for (int mt = 0; mt < 4; ++mt) {
#pragma unroll
    for (int i = 0; i < 2; ++i)
#pragma unroll
      for (int j = 0; j < 2; ++j) acc[i][j] = (f32x16)0.0f;

#pragma unroll
    for (int k6 = 0; k6 < 6; ++k6) {
      // issue next tile's loads first (overlap with compute below)
      const int nmt = (k6 == 5) ? mt + 1 : mt;
      const int nk6 = (k6 == 5) ? 0 : k6 + 1;
      if (nmt < 4) stage(cur ^ 1, nmt, nk6);

      // compute on buf 'cur'
      const int bufo = cur * 8192;
#pragma unroll
      for (int kb = 0; kb < 2; ++kb) {
        const int base = bufo + kb*4096;
        bf16x8 ah[2][2], bh[2][2];
#pragma unroll
        for (int i = 0; i < 2; ++i)
#pragma unroll
          for (int s = 0; s < 2; ++s) {
            int gra = ((s*2 + half) ^ gsw) * 8;
            int ro = base + (wr*64 + i*32 + l31)*32 + gra;
            ah[i][s] = *(const bf16x8*)&sMh[ro];
            int co = base + (wc*64 + i*32 + l31)*32 + gra;
            bh[i][s] = *(const bf16x8*)&sQh[co];
          }
#pragma unroll
        for (int i = 0; i < 2; ++i)
#pragma unroll
          for (int j = 0; j < 2; ++j)
#pragma unroll
            for (int s = 0; s < 2; ++s)
              acc[i][j] = __builtin_amdgcn_mfma_f32_32x32x16_bf16(ah[i][s], bh[j][s], acc[i][j], 0, 0, 0);
      }

      // epilogue for this mt overlaps the in-flight next-tile loads
      if (k6 == 5) {
#pragma unroll
        for (int i = 0; i < 2; ++i)
#pragma unroll
          for (int rg = 0; rg < 4; ++rg)
#pragma unroll
            for (int rr = 0; rr < 4; ++rr) {
              int rl = wr*64 + i*32 + half*4 + rr + 8*rg;
              float2 fa = sF[mt*128 + rl];
              unsigned int idx = (unsigned int)(((nc & 1) << 9) | (mt*128 + rl));
              float v0 = fmaf(acc[i][0][rg*4+rr], fa.x, fa.y);
              insert3b(keys[0], (__float_as_uint(v0) & 0xFFFFFC00u) | idx);
              float v1 = fmaf(acc[i][1][rg*4+rr], fa.x, fa.y);
              insert3b(keys[1], (__float_as_uint(v1) & 0xFFFFFC00u) | idx);
            }
      }

      // single barrier per step: drains vmcnt(0) for the loads issued above
      __syncthreads();
      cur ^= 1;
    }
  }

#pragma unroll
  for (int j = 0; j < 2; ++j) {
    int q_local = wc*64 + j*32 + l31;
    int c = wr*2 + half;
    size_t off = ((size_t)(qb*128 + q_local) * NC + nc) * 12 + c*3;
    keybuf[off+0] = keys[j][0];
    keybuf[off+1] = keys[j][1];
    keybuf[off+2] = keys[j][2];
  }
}

// == merge: block/query; tournament + exact rescore + fused seq gather-split ==
__global__ __launch_bounds__(256) void k_merge(
    const unsigned int* __restrict__ keybuf,
    const float* __restrict__ query, const float* __restrict__ memv,
    const float2* __restrict__ f2b,
    ushort_t* __restrict__ xsh, ushort_t* __restrict__ xsl) {
  __shared__ int sCand[16];
  __shared__ float sSimv[16];
  __shared__ int sTop[KK];
  const int tid = threadIdx.x, lane = tid & 63, wave = tid >> 6;
  const int q = blockIdx.x;

  if (wave == 0) {
    // lane covers chunks 2*lane, 2*lane+1: 24 contiguous keys
    const unsigned int* kb = keybuf + (size_t)q * (NC*12) + (size_t)lane * 24;
    unsigned int k5[5] = {0,0,0,0,0};
#pragma unroll
    for (int c = 0; c < 6; ++c) {
      uint4 v = *(const uint4*)(kb + c*4);
      insert5b(k5, v.x); insert5b(k5, v.y); insert5b(k5, v.z); insert5b(k5, v.w);
    }
#pragma unroll
    for (int p = 0; p < 16; ++p) {
      unsigned int bk = k5[0]; int blv = lane;
#pragma unroll
      for (int off = 1; off < 64; off <<= 1) {
        unsigned int ok = (unsigned int)__shfl_xor((int)bk, off);
        int ol = __shfl_xor(blv, off);
        if (ok > bk || (ok == bk && ol < blv)) { bk = ok; blv = ol; }
      }
      if (lane == blv) { k5[0]=k5[1]; k5[1]=k5[2]; k5[2]=k5[3]; k5[3]=k5[4]; k5[4]=0; }
      if (lane == 0) sCand[p] = (blv << 10) | (int)(bk & 1023u);
    }
  }
  __syncthreads();

  // each wave rescores 4 candidates in exact fp32
  float qv[6]; float sq = 0.f;
#pragma unroll
  for (int k = 0; k < 6; ++k) { qv[k] = query[(size_t)q*D + lane + 64*k]; sq += qv[k]*qv[k]; }
#pragma unroll
  for (int o = 32; o > 0; o >>= 1) sq += __shfl_xor(sq, o);
  float qn = sqrtf(sq);

#pragma unroll
  for (int pp = 0; pp < 4; ++pp) {
    int p = wave*4 + pp;
    int mi = sCand[p];
    float d = 0.f;
#pragma unroll
    for (int k = 0; k < 6; ++k) d += qv[k] * memv[(size_t)mi*D + lane + 64*k];
#pragma unroll
    for (int o = 32; o > 0; o >>= 1) d += __shfl_xor(d, o);
    if (lane == 0) {
      float2 fb = f2b[mi];
      sSimv[p] = d / fmaxf(qn * fb.x, FEPS) + fb.y;
    }
  }
  __syncthreads();

  if (tid == 0) {
    float cv[16]; int ci[16];
#pragma unroll
    for (int p = 0; p < 16; ++p) { cv[p] = sSimv[p]; ci[p] = sCand[p]; }
    for (int s = 0; s < KK; ++s) {
      int best = -1; float bv = -1e30f; int bi = 0x7FFFFFFF;
      for (int p = 0; p < 16; ++p) {
        if (ci[p] < 0) continue;
        if (cv[p] > bv || (cv[p] == bv && ci[p] < bi)) { best = p; bv = cv[p]; bi = ci[p]; }
      }
      sTop[s] = ci[best];
      ci[best] = -1;
    }
  }
  __syncthreads();

  // fused seq gather + hi/lo split: rows g = q*6 + t (t=0 query, t>0 retrieved)
#pragma unroll
  for (int rep = 0; rep < 2; ++rep) {
    int t = wave + rep*4;
    if (t < 6) {
      const float* src = (t == 0) ? (query + (size_t)q*D)
                                  : (memv + (size_t)sTop[t-1]*D);
      size_t g = (size_t)q*6 + t;
#pragma unroll
      for (int k = 0; k < 3; ++k) {
        float2 v = ((const float2*)src)[lane + 64*k];
        ushort_t h0 = f2bf(v.x), h1 = f2bf(v.y);
        ushort2 hh; hh.x = h0; hh.y = h1;
        ushort2 ll; ll.x = f2bf(v.x - bf2f(h0)); ll.y = f2bf(v.y - bf2f(h1));
        ((ushort2*)(xsh + g*D))[lane + 64*k] = hh;
        ((ushort2*)(xsl + g*D))[lane + 64*k] = ll;
      }
    }
  }
}

// ===== tail1: x_proj (contiguous seq rows, 96 tiles) + gate (16 tiles) + h1 =
// grid (112, 6); 64x64 tile, K=384 in 3 rounds of 4x32 subtiles; 3-term split
__global__ __launch_bounds__(256) void k_tail1(
    const ushort_t* __restrict__ xsh, const ushort_t* __restrict__ xsl,
    const ushort_t* __restrict__ wihh, const ushort_t* __restrict__ wihl,
    const ushort_t* __restrict__ wgh, const ushort_t* __restrict__ wgl,
    const float* __restrict__ b_ih, const float* __restrict__ b_hh,
    const float* __restrict__ b_g,
    float* __restrict__ xp, float* __restrict__ gate,
    ushort_t* __restrict__ hoh, ushort_t* __restrict__ hol) {
  __shared__ __align__(16) ushort_t sAh[64*128];
  __shared__ __align__(16) ushort_t sAl[64*128];
  __shared__ __align__(16) ushort_t sWh[64*128];
  __shared__ __align__(16) ushort_t sWl[64*128];

  const int tid = threadIdx.x, lane = tid & 63, wave = tid >> 6;
  const int wr = wave >> 1, wc = wave & 1;
  const int t = lane & 15, quad = lane >> 4;
  const bool xmode = blockIdx.x < 96;
  const int cbase = blockIdx.y * 64;
  const int rowoff = lane >> 2, koff = swz_koff(lane);
  const int pq = (quad ^ ((t >> 1) & 3)) * 8;    // swizzled read granule

  const ushort_t* gp[4];
  if (wave < 2) {
    const ushort_t* base = (wave == 0) ? xsh : xsl;
#pragma unroll
    for (int slot = 0; slot < 4; ++slot) {
      int rl = slot*16 + rowoff;
      size_t row = xmode ? (size_t)(blockIdx.x*64 + rl)
                         : (size_t)((blockIdx.x - 96)*64 + rl) * 6;
      gp[slot] = base + row*D + koff;
    }
  } else {
#pragma unroll
    for (int slot = 0; slot < 4; ++slot) {
      int rl = slot*16 + rowoff;
      const ushort_t* wsrc = xmode ? (wave == 2 ? wihh : wihl)
                                   : (wave == 2 ? wgh  : wgl);
      gp[slot] = wsrc + (size_t)(cbase + rl) * D + koff;
    }
  }
  ushort_t* ldst = (wave == 0) ? sAh : (wave == 1) ? sAl : (wave == 2) ? sWh : sWl;

  f32x4 acc[2][2];
#pragma unroll
  for (int i = 0; i < 2; ++i)
#pragma unroll
    for (int j = 0; j < 2; ++j) acc[i][j] = (f32x4)0.0f;

  for (int r3 = 0; r3 < 3; ++r3) {
    __syncthreads();
#pragma unroll
    for (int s = 0; s < 4; ++s)
#pragma unroll
      for (int slot = 0; slot < 4; ++slot)
        async16(gp[slot] + r3*128 + s*32, ldst + s*2048 + slot*512 + lane*8);
    __syncthreads();
#pragma unroll
    for (int s = 0; s < 4; ++s) {
      bf16x8 ah[2], al[2], bh[2], bl[2];
#pragma unroll
      for (int i = 0; i < 2; ++i) {
        int ro = s*2048 + (wr*32 + i*16 + t)*32 + pq;
        ah[i] = *(const bf16x8*)&sAh[ro];
        al[i] = *(const bf16x8*)&sAl[ro];
        int co = s*2048 + (wc*32 + i*16 + t)*32 + pq;
        bh[i] = *(const bf16x8*)&sWh[co];
        bl[i] = *(const bf16x8*)&sWl[co];
      }
#pragma unroll
      for (int i = 0; i < 2; ++i)
#pragma unroll
        for (int j = 0; j < 2; ++j) {
          acc[i][j] = __builtin_amdgcn_mfma_f32_16x16x32_bf16(ah[i], bh[j], acc[i][j], 0, 0, 0);
          acc[i][j] = __builtin_amdgcn_mfma_f32_16x16x32_bf16(ah[i], bl[j], acc[i][j], 0, 0, 0);
          acc[i][j] = __builtin_amdgcn_mfma_f32_16x16x32_bf16(al[i], bh[j], acc[i][j], 0, 0, 0);
        }
    }
  }

#pragma unroll
  for (int i = 0; i < 2; ++i)
#pragma unroll
    for (int j = 0; j < 2; ++j)
#pragma unroll
      for (int r = 0; r < 4; ++r) {
        int rloc = wr*32 + i*16 + quad*4 + r;
        int h = cbase + wc*32 + j*16 + t;
        float a = acc[i][j][r];
        if (xmode) {
          int g = blockIdx.x*64 + rloc;
          float v = a + b_ih[h];
          xp[(size_t)g*H + h] = v;
          int b = g / 6;
          if (g - b*6 == 0) {
            float hv = tanhf(v + b_hh[h]);
            ushort_t hi = f2bf(hv);
            hoh[(size_t)b*H + h] = hi;
            hol[(size_t)b*H + h] = f2bf(hv - bf2f(hi));
          }
        } else {
          int rq = (blockIdx.x - 96)*64 + rloc;
          gate[(size_t)rq*H + h] = 1.0f / (1.0f + expf(-(a + b_g[h])));
        }
      }
}

// ====== fused RNN steps 1..5: h' = tanh(x_t + h @ W_hh^T + b_hh) ===========
// grid (16, 6) = 96 blocks, all co-resident on 256 CUs; device-scope grid
// barrier between steps replaces 4 kernel launches. Step 5 fuses gated blend.
__global__ __launch_bounds__(256) void k_rnn_all(
    ushort_t* __restrict__ hAh, ushort_t* __restrict__ hAl,
    ushort_t* __restrict__ hBh, ushort_t* __restrict__ hBl,
    const ushort_t* __restrict__ whhh, const ushort_t* __restrict__ whhl,
    const float* __restrict__ b_hh, const float* __restrict__ xp,
    const float* __restrict__ gate,
    float* __restrict__ out, unsigned int* __restrict__ bar) {
  __shared__ __align__(16) ushort_t sAh[64*128];
  __shared__ __align__(16) ushort_t sAl[64*128];
  __shared__ __align__(16) ushort_t sWh[64*128];
  __shared__ __align__(16) ushort_t sWl[64*128];

  const int tid = threadIdx.x, lane = tid & 63, wave = tid >> 6;
  const int wr = wave >> 1, wc = wave & 1;
  const int t = lane & 15, quad = lane >> 4;
  const int rbase = blockIdx.x * 64, cbase = blockIdx.y * 64;
  const int rowoff = lane >> 2, koff = swz_koff(lane);
  const int pq = (quad ^ ((t >> 1) & 3)) * 8;
  const unsigned int nblk = gridDim.x * gridDim.y;   // 96

  // W pointers (waves 2-3) are step-invariant
  const ushort_t* gpw[4];
#pragma unroll
  for (int slot = 0; slot < 4; ++slot) {
    int rl = slot*16 + rowoff;
    gpw[slot] = ((wave == 2) ? whhh : whhl) + (size_t)(cbase + rl)*D + koff;
  }
  ushort_t* ldst = (wave == 0) ? sAh : (wave == 1) ? sAl : (wave == 2) ? sWh : sWl;

  for (int s = 1; s <= 5; ++s) {
    const ushort_t* ih = (s & 1) ? hAh : hBh;
    const ushort_t* il = (s & 1) ? hAl : hBl;
    ushort_t* oh = (s & 1) ? hBh : hAh;
    ushort_t* ol = (s & 1) ? hBl : hAl;

    const ushort_t* gp[4];
#pragma unroll
    for (int slot = 0; slot < 4; ++slot) {
      int rl = slot*16 + rowoff;
      gp[slot] = (wave >= 2) ? gpw[slot]
               : ((wave == 0) ? ih : il) + (size_t)(rbase + rl)*D + koff;
    }

    f32x4 acc[2][2];
#pragma unroll
    for (int i = 0; i < 2; ++i)
#pragma unroll
      for (int j = 0; j < 2; ++j) acc[i][j] = (f32x4)0.0f;

    for (int r3 = 0; r3 < 3; ++r3) {
      __syncthreads();
#pragma unroll
      for (int ss = 0; ss < 4; ++ss)
#pragma unroll
        for (int slot = 0; slot < 4; ++slot)
          async16(gp[slot] + r3*128 + ss*32, ldst + ss*2048 + slot*512 + lane*8);
      __syncthreads();
#pragma unroll
      for (int ss = 0; ss < 4; ++ss) {
        bf16x8 ah[2], al[2], bh[2], bl[2];
#pragma unroll
        for (int i = 0; i < 2; ++i) {
          int ro = ss*2048 + (wr*32 + i*16 + t)*32 + pq;
          ah[i] = *(const bf16x8*)&sAh[ro];
          al[i] = *(const bf16x8*)&sAl[ro];
          int co = ss*2048 + (wc*32 + i*16 + t)*32 + pq;
          bh[i] = *(const bf16x8*)&sWh[co];
          bl[i] = *(const bf16x8*)&sWl[co];
        }
#pragma unroll
        for (int i = 0; i < 2; ++i)
#pragma unroll
          for (int j = 0; j < 2; ++j) {
            acc[i][j] = __builtin_amdgcn_mfma_f32_16x16x32_bf16(ah[i], bh[j], acc[i][j], 0, 0, 0);
            acc[i][j] = __builtin_amdgcn_mfma_f32_16x16x32_bf16(ah[i], bl[j], acc[i][j], 0, 0, 0);
            acc[i][j] = __builtin_amdgcn_mfma_f32_16x16x32_bf16(al[i], bh[j], acc[i][j], 0, 0, 0);
          }
      }
    }

#pragma unroll
    for (int i = 0; i < 2; ++i)
#pragma unroll
      for (int j = 0; j < 2; ++j)
#pragma unroll
        for (int r = 0; r < 4; ++r) {
          int row = rbase + wr*32 + i*16 + quad*4 + r;
          int h = cbase + wc*32 + j*16 + t;
          float v = acc[i][j][r] + b_hh[h] + xp[(size_t)row*(6*H) + s*H + h];
          float hv = tanhf(v);
          if (s == 5) {
            float g = gate[(size_t)row*H + h];
            out[(size_t)row*H + h] = g*hv + (1.0f - g)*xp[(size_t)row*(6*H) + h];
          } else {
            ushort_t hi = f2bf(hv);
            oh[(size_t)row*H + h] = hi;
            ol[(size_t)row*H + h] = f2bf(hv - bf2f(hi));
          }
        }

    if (s < 5) grid_barrier(bar, nblk * (unsigned)s);
  }
}

} // namespace

extern "C" void kernel_launch(void* const* d_in, const int* in_sizes, int n_in,
                              void* d_out, int out_size, void* d_ws, size_t ws_size,
                              hipStream_t stream) {
  const float* query = (const float*)d_in[0];
  const float* memv  = (const float*)d_in[1];
  const float* coords= (const float*)d_in[2];
  const float* sw    = (const float*)d_in[3];
  const float* W_ih  = (const float*)d_in[4];
  const float* b_ih  = (const float*)d_in[5];
  const float* W_hh  = (const float*)d_in[6];
  const float* b_hh  = (const float*)d_in[7];
  const float* W_g   = (const float*)d_in[8];
  const float* b_g   = (const float*)d_in[9];
  float* out = (float*)d_out;

  char* p = (char*)d_ws;
  auto alloc = [&](size_t bytes) {
    char* r = p; p += (bytes + 255) & ~(size_t)255; return r;
  };
  ushort_t* qh  = (ushort_t*)alloc((size_t)B * D * 2);
  ushort_t* mh  = (ushort_t*)alloc((size_t)M * D * 2);
  float2* f2a   = (float2*)alloc((size_t)M * 8);
  float2* f2b   = (float2*)alloc((size_t)M * 8);
  ushort_t* wihh = (ushort_t*)alloc((size_t)H * D * 2);
  ushort_t* wihl = (ushort_t*)alloc((size_t)H * D * 2);
  ushort_t* whhh = (ushort_t*)alloc((size_t)H * D * 2);
  ushort_t* whhl = (ushort_t*)alloc((size_t)H * D * 2);
  ushort_t* wgh  = (ushort_t*)alloc((size_t)H * D * 2);
  ushort_t* wgl  = (ushort_t*)alloc((size_t)H * D * 2);
  unsigned int* keybuf = (unsigned int*)alloc((size_t)B * NC * 12 * 4);
  ushort_t* xsh = (ushort_t*)alloc((size_t)B * 6 * D * 2);
  ushort_t* xsl = (ushort_t*)alloc((size_t)B * 6 * D * 2);
  float* xp     = (float*)alloc((size_t)B * 6 * H * 4);
  float* gate   = (float*)alloc((size_t)B * H * 4);
  ushort_t* hAh = (ushort_t*)alloc((size_t)B * H * 2);
  ushort_t* hAl = (ushort_t*)alloc((size_t)B * H * 2);
  ushort_t* hBh = (ushort_t*)alloc((size_t)B * H * 2);
  ushort_t* hBl = (ushort_t*)alloc((size_t)B * H * 2);
  unsigned int* bar = (unsigned int*)alloc(256);

  k_prep<<<M/4 + B/4 + 288, 256, 0, stream>>>(
      query, memv, coords, sw, W_ih, W_hh, W_g,
      qh, mh, f2a, f2b,
      wihh, wihl, whhh, whhl, wgh, wgl, bar);
  k_sim<<<1024, 256, 0, stream>>>(qh, mh, f2a, keybuf);
  k_merge<<<B, 256, 0, stream>>>(keybuf, query, memv, f2b, xsh, xsl);
  k_tail1<<<dim3(112, 6), 256, 0, stream>>>(
      xsh, xsl, wihh, wihl, wgh, wgl,
      b_ih, b_hh, b_g, xp, gate, hAh, hAl);
  k_rnn_all<<<dim3(16, 6), 256, 0, stream>>>(
      hAh, hAl, hBh, hBl, whhh, whhl, b_hh, xp, gate, out, bar);
}

// Round 7
// 333.857 us; speedup vs baseline: 1.2095x; 1.2095x over previous
//
#include <hip/hip_runtime.h>
#include <math.h>

namespace {

typedef float f32x4 __attribute__((ext_vector_type(4)));
typedef float f32x16 __attribute__((ext_vector_type(16)));
typedef short bf16x8 __attribute__((ext_vector_type(8)));
typedef unsigned short ushort_t;

constexpr int B  = 1024;
constexpr int M  = 65536;
constexpr int D  = 384;
constexpr int H  = 384;
constexpr int KK = 5;
constexpr int NC = 128;         // chunks over M
constexpr int CHUNK = M / NC;   // 512 mems per chunk
constexpr float FEPS = 1e-8f;

__device__ __forceinline__ ushort_t f2bf(float x) {
  unsigned int u = __float_as_uint(x);
  unsigned int r = (u + 0x7FFFu + ((u >> 16) & 1u)) >> 16;   // RNE
  return (ushort_t)r;
}
__device__ __forceinline__ float bf2f(ushort_t h) {
  return __uint_as_float(((unsigned int)h) << 16);
}

__device__ __forceinline__ void async16(const ushort_t* g, ushort_t* l) {
  __builtin_amdgcn_global_load_lds(
      (const __attribute__((address_space(1))) unsigned int*)g,
      (__attribute__((address_space(3))) unsigned int*)l, 16, 0, 0);
}

__device__ __forceinline__ void insert3b(unsigned int* k, unsigned int v) {
  unsigned int t0 = min(k[0], v); k[0] = max(k[0], v);
  unsigned int t1 = min(k[1], t0); k[1] = max(k[1], t0);
  k[2] = max(k[2], t1);
}
__device__ __forceinline__ void insert5b(unsigned int* k, unsigned int v) {
  unsigned int t0 = min(k[0], v); k[0] = max(k[0], v);
  unsigned int t1 = min(k[1], t0); k[1] = max(k[1], t0);
  unsigned int t2 = min(k[2], t1); k[2] = max(k[2], t1);
  unsigned int t3 = min(k[3], t2); k[3] = max(k[3], t2);
  k[4] = max(k[4], t3);
}

// swizzled per-lane global k-offset for staging: LDS granule (lane&3) of row
// (lane>>2) holds logical granule (lane&3) ^ ((row>>1)&3).  [bank-conflict fix]
__device__ __forceinline__ int swz_koff(int lane) {
  return (((lane & 3) ^ ((lane >> 3) & 3)) * 8);
}

// ======= prep: mem hi-split+stats | q norm-hi | weight hi/lo splits =========
__global__ __launch_bounds__(256) void k_prep(
    const float* __restrict__ q, const float* __restrict__ mem,
    const float* __restrict__ coords, const float* __restrict__ sw,
    const float* __restrict__ W_ih, const float* __restrict__ W_hh,
    const float* __restrict__ W_g,
    ushort_t* __restrict__ qh, ushort_t* __restrict__ mh,
    float2* __restrict__ f2a, float2* __restrict__ f2b,
    ushort_t* __restrict__ wihh, ushort_t* __restrict__ wihl,
    ushort_t* __restrict__ whhh, ushort_t* __restrict__ whhl,
    ushort_t* __restrict__ wgh, ushort_t* __restrict__ wgl) {
  int wv = threadIdx.x >> 6, lane = threadIdx.x & 63;
  int bid = blockIdx.x;
  if (bid < M/4) {
    int r = bid*4 + wv;
    float cx = 0.f, cy = 0.f;
    for (int i = lane; i < H; i += 64) { cx += sw[2*i]; cy += sw[2*i+1]; }
#pragma unroll
    for (int o = 32; o > 0; o >>= 1) { cx += __shfl_xor(cx, o); cy += __shfl_xor(cy, o); }
    cx *= (1.0f/384.0f); cy *= (1.0f/384.0f);
    float2 x[3]; float s = 0.f;
#pragma unroll
    for (int k = 0; k < 3; ++k) {
      x[k] = ((const float2*)(mem + (size_t)r*D))[lane + 64*k];
      s += x[k].x*x[k].x + x[k].y*x[k].y;
    }
#pragma unroll
    for (int o = 32; o > 0; o >>= 1) s += __shfl_xor(s, o);
#pragma unroll
    for (int k = 0; k < 3; ++k) {
      ushort2 hh; hh.x = f2bf(x[k].x); hh.y = f2bf(x[k].y);
      ((ushort2*)(mh + (size_t)r*D))[lane + 64*k] = hh;
    }
    if (lane == 0) {
      float mn = sqrtf(s);
      float dx = coords[2*r] - cx, dy = coords[2*r+1] - cy;
      float act = 1.0f / (1.0f + sqrtf(dx*dx + dy*dy));
      f2a[r] = make_float2(1.0f / mn, act + 2.0f);
      f2b[r] = make_float2(mn, act);
    }
  } else if (bid < M/4 + B/4) {
    int r = (bid - M/4)*4 + wv;
    float2 x[3]; float s = 0.f;
#pragma unroll
    for (int k = 0; k < 3; ++k) {
      x[k] = ((const float2*)(q + (size_t)r*D))[lane + 64*k];
      s += x[k].x*x[k].x + x[k].y*x[k].y;
    }
#pragma unroll
    for (int o = 32; o > 0; o >>= 1) s += __shfl_xor(s, o);
    float inv = 1.0f / sqrtf(s);
#pragma unroll
    for (int k = 0; k < 3; ++k) {
      ushort2 nn; nn.x = f2bf(x[k].x * inv); nn.y = f2bf(x[k].y * inv);
      ((ushort2*)(qh + (size_t)r*D))[lane + 64*k] = nn;
    }
  } else {
    int r = (bid - M/4 - B/4)*4 + wv;   // 0..1151
    const float* src; ushort_t* dh; ushort_t* dl;
    if (r < 384)      { src = W_ih + (size_t)r*D;       dh = wihh + (size_t)r*D;       dl = wihl + (size_t)r*D; }
    else if (r < 768) { src = W_hh + (size_t)(r-384)*D; dh = whhh + (size_t)(r-384)*D; dl = whhl + (size_t)(r-384)*D; }
    else              { src = W_g  + (size_t)(r-768)*D; dh = wgh  + (size_t)(r-768)*D; dl = wgl  + (size_t)(r-768)*D; }
#pragma unroll
    for (int k = 0; k < 3; ++k) {
      float2 v = ((const float2*)src)[lane + 64*k];
      ushort_t h0 = f2bf(v.x), h1 = f2bf(v.y);
      ushort2 hh; hh.x = h0; hh.y = h1;
      ushort2 ll; ll.x = f2bf(v.x - bf2f(h0)); ll.y = f2bf(v.y - bf2f(h1));
      ((ushort2*)dh)[lane + 64*k] = hh;
      ((ushort2*)dl)[lane + 64*k] = ll;
    }
  }
}

// ====== sim: 1-term mh x qh 32x32x16 MFMA, BK=64, double-buffered 2-phase ===
// 1D grid 1024; XCD-aware decode: the 8 q-tiles sharing chunk nc are
// consecutive on XCD nc%8 -> chunk read from HBM once, L2-hit 7x.
__global__ __launch_bounds__(256, 2) void k_sim(
    const ushort_t* __restrict__ qh,
    const ushort_t* __restrict__ mh,
    const float2* __restrict__ f2a, unsigned int* __restrict__ keybuf) {
  __shared__ __align__(16) ushort_t sQh[2*8192];   // [buf][kb*4096+slot*512+lane*8]
  __shared__ __align__(16) ushort_t sMh[2*8192];
  __shared__ __align__(16) float2 sF[CHUNK];   // per-chunk (1/mn, act+2)

  const int tid = threadIdx.x, lane = tid & 63, wave = tid >> 6;
  const int wr = wave >> 1, wc = wave & 1;
  const int l31 = lane & 31, half = lane >> 5;
  const int flat = blockIdx.x;
  const int k8 = flat & 7, qb = (flat >> 3) & 7, mgrp = flat >> 6;
  const int nc = (mgrp << 3) | k8;
  const int rowoff = lane >> 2, koff = swz_koff(lane);
  const int gsw = (l31 >> 1) & 3;          // read-side swizzle
  const size_t qrow0 = (size_t)qb * 128;

  // stage chunk stats once (coalesced): 256 x float4 = 512 float2
  ((float4*)sF)[tid] = ((const float4*)(f2a + (size_t)nc * CHUNK))[tid];

  // per-wave slot decode for staging (same addressing as before)
  auto stage = [&](int buf, int mt, int k6) {
    const size_t mrow0 = (size_t)nc * CHUNK + (size_t)mt * 128;
    const int kt = k6 * 64;
#pragma unroll
    for (int n = 0; n < 8; ++n) {
      int f = wave*8 + n;
      int arr = f >> 4, sub = f & 15, kb = sub >> 3, slot = sub & 7;
      const ushort_t* src = arr == 0 ? qh : mh;
      ushort_t* dst = (arr == 0 ? sQh : sMh) + buf*8192;
      size_t rowb = arr == 0 ? qrow0 : mrow0;
      async16(src + (rowb + slot*16 + rowoff)*D + kt + kb*32 + koff,
              dst + kb*4096 + slot*512 + lane*8);
    }
  };

  unsigned int keys[2][3];
#pragma unroll
  for (int j = 0; j < 2; ++j) { keys[j][0] = 0; keys[j][1] = 0; keys[j][2] = 0; }

  // prologue: stage (mt=0,k6=0) into buf 0, drain
  stage(0, 0, 0);
  __syncthreads();

  int cur = 0;
  f32x16 acc[2][2];

  for (int mt = 0; mt < 4; ++mt) {
#pragma unroll
    for (int i = 0; i < 2; ++i)
#pragma unroll
      for (int j = 0; j < 2; ++j) acc[i][j] = (f32x16)0.0f;

#pragma unroll
    for (int k6 = 0; k6 < 6; ++k6) {
      // issue next tile's loads first (overlap with compute below)
      const int nmt = (k6 == 5) ? mt + 1 : mt;
      const int nk6 = (k6 == 5) ? 0 : k6 + 1;
      if (nmt < 4) stage(cur ^ 1, nmt, nk6);

      // compute on buf 'cur'
      const int bufo = cur * 8192;
#pragma unroll
      for (int kb = 0; kb < 2; ++kb) {
        const int base = bufo + kb*4096;
        bf16x8 ah[2][2], bh[2][2];
#pragma unroll
        for (int i = 0; i < 2; ++i)
#pragma unroll
          for (int s = 0; s < 2; ++s) {
            int gra = ((s*2 + half) ^ gsw) * 8;
            int ro = base + (wr*64 + i*32 + l31)*32 + gra;
            ah[i][s] = *(const bf16x8*)&sMh[ro];
            int co = base + (wc*64 + i*32 + l31)*32 + gra;
            bh[i][s] = *(const bf16x8*)&sQh[co];
          }
#pragma unroll
        for (int i = 0; i < 2; ++i)
#pragma unroll
          for (int j = 0; j < 2; ++j)
#pragma unroll
            for (int s = 0; s < 2; ++s)
              acc[i][j] = __builtin_amdgcn_mfma_f32_32x32x16_bf16(ah[i][s], bh[j][s], acc[i][j], 0, 0, 0);
      }

      // epilogue for this mt overlaps the in-flight next-tile loads
      if (k6 == 5) {
#pragma unroll
        for (int i = 0; i < 2; ++i)
#pragma unroll
          for (int rg = 0; rg < 4; ++rg)
#pragma unroll
            for (int rr = 0; rr < 4; ++rr) {
              int rl = wr*64 + i*32 + half*4 + rr + 8*rg;
              float2 fa = sF[mt*128 + rl];
              unsigned int idx = (unsigned int)(((nc & 1) << 9) | (mt*128 + rl));
              float v0 = fmaf(acc[i][0][rg*4+rr], fa.x, fa.y);
              insert3b(keys[0], (__float_as_uint(v0) & 0xFFFFFC00u) | idx);
              float v1 = fmaf(acc[i][1][rg*4+rr], fa.x, fa.y);
              insert3b(keys[1], (__float_as_uint(v1) & 0xFFFFFC00u) | idx);
            }
      }

      // single barrier per step: drains vmcnt(0) for the loads issued above
      __syncthreads();
      cur ^= 1;
    }
  }

#pragma unroll
  for (int j = 0; j < 2; ++j) {
    int q_local = wc*64 + j*32 + l31;
    int c = wr*2 + half;
    size_t off = ((size_t)(qb*128 + q_local) * NC + nc) * 12 + c*3;
    keybuf[off+0] = keys[j][0];
    keybuf[off+1] = keys[j][1];
    keybuf[off+2] = keys[j][2];
  }
}

// == merge: block/query; tournament + exact rescore + fused seq gather-split ==
__global__ __launch_bounds__(256) void k_merge(
    const unsigned int* __restrict__ keybuf,
    const float* __restrict__ query, const float* __restrict__ memv,
    const float2* __restrict__ f2b,
    ushort_t* __restrict__ xsh, ushort_t* __restrict__ xsl) {
  __shared__ int sCand[16];
  __shared__ float sSimv[16];
  __shared__ int sTop[KK];
  const int tid = threadIdx.x, lane = tid & 63, wave = tid >> 6;
  const int q = blockIdx.x;

  if (wave == 0) {
    // lane covers chunks 2*lane, 2*lane+1: 24 contiguous keys
    const unsigned int* kb = keybuf + (size_t)q * (NC*12) + (size_t)lane * 24;
    unsigned int k5[5] = {0,0,0,0,0};
#pragma unroll
    for (int c = 0; c < 6; ++c) {
      uint4 v = *(const uint4*)(kb + c*4);
      insert5b(k5, v.x); insert5b(k5, v.y); insert5b(k5, v.z); insert5b(k5, v.w);
    }
#pragma unroll
    for (int p = 0; p < 16; ++p) {
      unsigned int bk = k5[0]; int blv = lane;
#pragma unroll
      for (int off = 1; off < 64; off <<= 1) {
        unsigned int ok = (unsigned int)__shfl_xor((int)bk, off);
        int ol = __shfl_xor(blv, off);
        if (ok > bk || (ok == bk && ol < blv)) { bk = ok; blv = ol; }
      }
      if (lane == blv) { k5[0]=k5[1]; k5[1]=k5[2]; k5[2]=k5[3]; k5[3]=k5[4]; k5[4]=0; }
      if (lane == 0) sCand[p] = (blv << 10) | (int)(bk & 1023u);
    }
  }
  __syncthreads();

  // each wave rescores 4 candidates in exact fp32
  float qv[6]; float sq = 0.f;
#pragma unroll
  for (int k = 0; k < 6; ++k) { qv[k] = query[(size_t)q*D + lane + 64*k]; sq += qv[k]*qv[k]; }
#pragma unroll
  for (int o = 32; o > 0; o >>= 1) sq += __shfl_xor(sq, o);
  float qn = sqrtf(sq);

#pragma unroll
  for (int pp = 0; pp < 4; ++pp) {
    int p = wave*4 + pp;
    int mi = sCand[p];
    float d = 0.f;
#pragma unroll
    for (int k = 0; k < 6; ++k) d += qv[k] * memv[(size_t)mi*D + lane + 64*k];
#pragma unroll
    for (int o = 32; o > 0; o >>= 1) d += __shfl_xor(d, o);
    if (lane == 0) {
      float2 fb = f2b[mi];
      sSimv[p] = d / fmaxf(qn * fb.x, FEPS) + fb.y;
    }
  }
  __syncthreads();

  if (tid == 0) {
    float cv[16]; int ci[16];
#pragma unroll
    for (int p = 0; p < 16; ++p) { cv[p] = sSimv[p]; ci[p] = sCand[p]; }
    for (int s = 0; s < KK; ++s) {
      int best = -1; float bv = -1e30f; int bi = 0x7FFFFFFF;
      for (int p = 0; p < 16; ++p) {
        if (ci[p] < 0) continue;
        if (cv[p] > bv || (cv[p] == bv && ci[p] < bi)) { best = p; bv = cv[p]; bi = ci[p]; }
      }
      sTop[s] = ci[best];
      ci[best] = -1;
    }
  }
  __syncthreads();

  // fused seq gather + hi/lo split: rows g = q*6 + t (t=0 query, t>0 retrieved)
#pragma unroll
  for (int rep = 0; rep < 2; ++rep) {
    int t = wave + rep*4;
    if (t < 6) {
      const float* src = (t == 0) ? (query + (size_t)q*D)
                                  : (memv + (size_t)sTop[t-1]*D);
      size_t g = (size_t)q*6 + t;
#pragma unroll
      for (int k = 0; k < 3; ++k) {
        float2 v = ((const float2*)src)[lane + 64*k];
        ushort_t h0 = f2bf(v.x), h1 = f2bf(v.y);
        ushort2 hh; hh.x = h0; hh.y = h1;
        ushort2 ll; ll.x = f2bf(v.x - bf2f(h0)); ll.y = f2bf(v.y - bf2f(h1));
        ((ushort2*)(xsh + g*D))[lane + 64*k] = hh;
        ((ushort2*)(xsl + g*D))[lane + 64*k] = ll;
      }
    }
  }
}

// ===== tail1: x_proj (contiguous seq rows, 96 tiles) + gate (16 tiles) + h1 =
// grid (112, 6); 64x64 tile, K=384 in 3 rounds of 4x32 subtiles; 3-term split
__global__ __launch_bounds__(256) void k_tail1(
    const ushort_t* __restrict__ xsh, const ushort_t* __restrict__ xsl,
    const ushort_t* __restrict__ wihh, const ushort_t* __restrict__ wihl,
    const ushort_t* __restrict__ wgh, const ushort_t* __restrict__ wgl,
    const float* __restrict__ b_ih, const float* __restrict__ b_hh,
    const float* __restrict__ b_g,
    float* __restrict__ xp, float* __restrict__ gate,
    ushort_t* __restrict__ hoh, ushort_t* __restrict__ hol) {
  __shared__ __align__(16) ushort_t sAh[64*128];
  __shared__ __align__(16) ushort_t sAl[64*128];
  __shared__ __align__(16) ushort_t sWh[64*128];
  __shared__ __align__(16) ushort_t sWl[64*128];

  const int tid = threadIdx.x, lane = tid & 63, wave = tid >> 6;
  const int wr = wave >> 1, wc = wave & 1;
  const int t = lane & 15, quad = lane >> 4;
  const bool xmode = blockIdx.x < 96;
  const int cbase = blockIdx.y * 64;
  const int rowoff = lane >> 2, koff = swz_koff(lane);
  const int pq = (quad ^ ((t >> 1) & 3)) * 8;    // swizzled read granule

  const ushort_t* gp[4];
  if (wave < 2) {
    const ushort_t* base = (wave == 0) ? xsh : xsl;
#pragma unroll
    for (int slot = 0; slot < 4; ++slot) {
      int rl = slot*16 + rowoff;
      size_t row = xmode ? (size_t)(blockIdx.x*64 + rl)
                         : (size_t)((blockIdx.x - 96)*64 + rl) * 6;
      gp[slot] = base + row*D + koff;
    }
  } else {
#pragma unroll
    for (int slot = 0; slot < 4; ++slot) {
      int rl = slot*16 + rowoff;
      const ushort_t* wsrc = xmode ? (wave == 2 ? wihh : wihl)
                                   : (wave == 2 ? wgh  : wgl);
      gp[slot] = wsrc + (size_t)(cbase + rl) * D + koff;
    }
  }
  ushort_t* ldst = (wave == 0) ? sAh : (wave == 1) ? sAl : (wave == 2) ? sWh : sWl;

  f32x4 acc[2][2];
#pragma unroll
  for (int i = 0; i < 2; ++i)
#pragma unroll
    for (int j = 0; j < 2; ++j) acc[i][j] = (f32x4)0.0f;

  for (int r3 = 0; r3 < 3; ++r3) {
    __syncthreads();
#pragma unroll
    for (int s = 0; s < 4; ++s)
#pragma unroll
      for (int slot = 0; slot < 4; ++slot)
        async16(gp[slot] + r3*128 + s*32, ldst + s*2048 + slot*512 + lane*8);
    __syncthreads();
#pragma unroll
    for (int s = 0; s < 4; ++s) {
      bf16x8 ah[2], al[2], bh[2], bl[2];
#pragma unroll
      for (int i = 0; i < 2; ++i) {
        int ro = s*2048 + (wr*32 + i*16 + t)*32 + pq;
        ah[i] = *(const bf16x8*)&sAh[ro];
        al[i] = *(const bf16x8*)&sAl[ro];
        int co = s*2048 + (wc*32 + i*16 + t)*32 + pq;
        bh[i] = *(const bf16x8*)&sWh[co];
        bl[i] = *(const bf16x8*)&sWl[co];
      }
#pragma unroll
      for (int i = 0; i < 2; ++i)
#pragma unroll
        for (int j = 0; j < 2; ++j) {
          acc[i][j] = __builtin_amdgcn_mfma_f32_16x16x32_bf16(ah[i], bh[j], acc[i][j], 0, 0, 0);
          acc[i][j] = __builtin_amdgcn_mfma_f32_16x16x32_bf16(ah[i], bl[j], acc[i][j], 0, 0, 0);
          acc[i][j] = __builtin_amdgcn_mfma_f32_16x16x32_bf16(al[i], bh[j], acc[i][j], 0, 0, 0);
        }
    }
  }

#pragma unroll
  for (int i = 0; i < 2; ++i)
#pragma unroll
    for (int j = 0; j < 2; ++j)
#pragma unroll
      for (int r = 0; r < 4; ++r) {
        int rloc = wr*32 + i*16 + quad*4 + r;
        int h = cbase + wc*32 + j*16 + t;
        float a = acc[i][j][r];
        if (xmode) {
          int g = blockIdx.x*64 + rloc;
          float v = a + b_ih[h];
          xp[(size_t)g*H + h] = v;
          int b = g / 6;
          if (g - b*6 == 0) {
            float hv = tanhf(v + b_hh[h]);
            ushort_t hi = f2bf(hv);
            hoh[(size_t)b*H + h] = hi;
            hol[(size_t)b*H + h] = f2bf(hv - bf2f(hi));
          }
        } else {
          int rq = (blockIdx.x - 96)*64 + rloc;
          gate[(size_t)rq*H + h] = 1.0f / (1.0f + expf(-(a + b_g[h])));
        }
      }
}

// ========= RNN step: h' = tanh(x_t + h @ W_hh^T + b_hh), 32x64 tiles =======
// grid (32, 6) = 192 blocks (2x the old 16x6 -> 75% CU util). Same 2-barrier
// schedule and identical per-element math order as the verified 64x64 k_rnn;
// only row decode changes: waves 0/1 stage 32 A-rows (2 slots), each wave
// computes 1x2 C-tiles (wr = 16-row group, wc = 32-col group).
template<int LAST>
__global__ __launch_bounds__(256) void k_rnn(
    const ushort_t* __restrict__ hih, const ushort_t* __restrict__ hil,
    const ushort_t* __restrict__ whhh, const ushort_t* __restrict__ whhl,
    const float* __restrict__ b_hh, const float* __restrict__ xp,
    const float* __restrict__ gate, int step,
    ushort_t* __restrict__ hoh, ushort_t* __restrict__ hol,
    float* __restrict__ out) {
  __shared__ __align__(16) ushort_t sAh[32*128];
  __shared__ __align__(16) ushort_t sAl[32*128];
  __shared__ __align__(16) ushort_t sWh[64*128];
  __shared__ __align__(16) ushort_t sWl[64*128];

  const int tid = threadIdx.x, lane = tid & 63, wave = tid >> 6;
  const int wr = wave >> 1, wc = wave & 1;
  const int t = lane & 15, quad = lane >> 4;
  const int rbase = blockIdx.x * 32, cbase = blockIdx.y * 64;
  const int rowoff = lane >> 2, koff = swz_koff(lane);
  const int pq = (quad ^ ((t >> 1) & 3)) * 8;
  const int nslot = (wave < 2) ? 2 : 4;           // A: 32 rows, W: 64 cols
  const int sstride = (wave < 2) ? 1024 : 2048;   // LDS subtile stride (ushorts)

  const ushort_t* gp[4];
#pragma unroll
  for (int slot = 0; slot < 4; ++slot) {
    int rl = slot*16 + rowoff;
    const ushort_t* src =
        (wave == 0) ? hih + (size_t)(rbase + rl)*D :
        (wave == 1) ? hil + (size_t)(rbase + rl)*D :
        (wave == 2) ? whhh + (size_t)(cbase + rl)*D :
                      whhl + (size_t)(cbase + rl)*D;
    gp[slot] = src + koff;
  }
  ushort_t* ldst = (wave == 0) ? sAh : (wave == 1) ? sAl : (wave == 2) ? sWh : sWl;

  f32x4 acc[2];
#pragma unroll
  for (int j = 0; j < 2; ++j) acc[j] = (f32x4)0.0f;

  for (int r3 = 0; r3 < 3; ++r3) {
    __syncthreads();
#pragma unroll
    for (int s = 0; s < 4; ++s)
      for (int slot = 0; slot < nslot; ++slot)
        async16(gp[slot] + r3*128 + s*32, ldst + s*sstride + slot*512 + lane*8);
    __syncthreads();
#pragma unroll
    for (int s = 0; s < 4; ++s) {
      int ro = s*1024 + (wr*16 + t)*32 + pq;
      bf16x8 ah = *(const bf16x8*)&sAh[ro];
      bf16x8 al = *(const bf16x8*)&sAl[ro];
      bf16x8 bh[2], bl[2];
#pragma unroll
      for (int j = 0; j < 2; ++j) {
        int co = s*2048 + (wc*32 + j*16 + t)*32 + pq;
        bh[j] = *(const bf16x8*)&sWh[co];
        bl[j] = *(const bf16x8*)&sWl[co];
      }
#pragma unroll
      for (int j = 0; j < 2; ++j) {
        acc[j] = __builtin_amdgcn_mfma_f32_16x16x32_bf16(ah, bh[j], acc[j], 0, 0, 0);
        acc[j] = __builtin_amdgcn_mfma_f32_16x16x32_bf16(ah, bl[j], acc[j], 0, 0, 0);
        acc[j] = __builtin_amdgcn_mfma_f32_16x16x32_bf16(al, bh[j], acc[j], 0, 0, 0);
      }
    }
  }

#pragma unroll
  for (int j = 0; j < 2; ++j)
#pragma unroll
    for (int r = 0; r < 4; ++r) {
      int row = rbase + wr*16 + quad*4 + r;
      int h = cbase + wc*32 + j*16 + t;
      float v = acc[j][r] + b_hh[h] + xp[(size_t)row*(6*H) + step*H + h];
      float hv = tanhf(v);
      if (LAST) {
        float g = gate[(size_t)row*H + h];
        out[(size_t)row*H + h] = g*hv + (1.0f - g)*xp[(size_t)row*(6*H) + h];
      } else {
        ushort_t hi = f2bf(hv);
        hoh[(size_t)row*H + h] = hi;
        hol[(size_t)row*H + h] = f2bf(hv - bf2f(hi));
      }
    }
}

} // namespace

extern "C" void kernel_launch(void* const* d_in, const int* in_sizes, int n_in,
                              void* d_out, int out_size, void* d_ws, size_t ws_size,
                              hipStream_t stream) {
  const float* query = (const float*)d_in[0];
  const float* memv  = (const float*)d_in[1];
  const float* coords= (const float*)d_in[2];
  const float* sw    = (const float*)d_in[3];
  const float* W_ih  = (const float*)d_in[4];
  const float* b_ih  = (const float*)d_in[5];
  const float* W_hh  = (const float*)d_in[6];
  const float* b_hh  = (const float*)d_in[7];
  const float* W_g   = (const float*)d_in[8];
  const float* b_g   = (const float*)d_in[9];
  float* out = (float*)d_out;

  char* p = (char*)d_ws;
  auto alloc = [&](size_t bytes) {
    char* r = p; p += (bytes + 255) & ~(size_t)255; return r;
  };
  ushort_t* qh  = (ushort_t*)alloc((size_t)B * D * 2);
  ushort_t* mh  = (ushort_t*)alloc((size_t)M * D * 2);
  float2* f2a   = (float2*)alloc((size_t)M * 8);
  float2* f2b   = (float2*)alloc((size_t)M * 8);
  ushort_t* wihh = (ushort_t*)alloc((size_t)H * D * 2);
  ushort_t* wihl = (ushort_t*)alloc((size_t)H * D * 2);
  ushort_t* whhh = (ushort_t*)alloc((size_t)H * D * 2);
  ushort_t* whhl = (ushort_t*)alloc((size_t)H * D * 2);
  ushort_t* wgh  = (ushort_t*)alloc((size_t)H * D * 2);
  ushort_t* wgl  = (ushort_t*)alloc((size_t)H * D * 2);
  unsigned int* keybuf = (unsigned int*)alloc((size_t)B * NC * 12 * 4);
  ushort_t* xsh = (ushort_t*)alloc((size_t)B * 6 * D * 2);
  ushort_t* xsl = (ushort_t*)alloc((size_t)B * 6 * D * 2);
  float* xp     = (float*)alloc((size_t)B * 6 * H * 4);
  float* gate   = (float*)alloc((size_t)B * H * 4);
  ushort_t* hAh = (ushort_t*)alloc((size_t)B * H * 2);
  ushort_t* hAl = (ushort_t*)alloc((size_t)B * H * 2);
  ushort_t* hBh = (ushort_t*)alloc((size_t)B * H * 2);
  ushort_t* hBl = (ushort_t*)alloc((size_t)B * H * 2);

  k_prep<<<M/4 + B/4 + 288, 256, 0, stream>>>(
      query, memv, coords, sw, W_ih, W_hh, W_g,
      qh, mh, f2a, f2b,
      wihh, wihl, whhh, whhl, wgh, wgl);
  k_sim<<<1024, 256, 0, stream>>>(qh, mh, f2a, keybuf);
  k_merge<<<B, 256, 0, stream>>>(keybuf, query, memv, f2b, xsh, xsl);
  k_tail1<<<dim3(112, 6), 256, 0, stream>>>(
      xsh, xsl, wihh, wihl, wgh, wgl,
      b_ih, b_hh, b_g, xp, gate, hAh, hAl);
  k_rnn<0><<<dim3(32, 6), 256, 0, stream>>>(hAh, hAl, whhh, whhl, b_hh, xp, gate, 1, hBh, hBl, out);
  k_rnn<0><<<dim3(32, 6), 256, 0, stream>>>(hBh, hBl, whhh, whhl, b_hh, xp, gate, 2, hAh, hAl, out);
  k_rnn<0><<<dim3(32, 6), 256, 0, stream>>>(hAh, hAl, whhh, whhl, b_hh, xp, gate, 3, hBh, hBl, out);
  k_rnn<0><<<dim3(32, 6), 256, 0, stream>>>(hBh, hBl, whhh, whhl, b_hh, xp, gate, 4, hAh, hAl, out);
  k_rnn<1><<<dim3(32, 6), 256, 0, stream>>>(hAh, hAl, whhh, whhl, b_hh, xp, gate, 5, hBh, hBl, out);
}

// Round 9
// 319.237 us; speedup vs baseline: 1.2649x; 1.0458x over previous
//
#include <hip/hip_runtime.h>
#include <math.h>

namespace {

typedef float f32x4 __attribute__((ext_vector_type(4)));
typedef float f32x16 __attribute__((ext_vector_type(16)));
typedef short bf16x8 __attribute__((ext_vector_type(8)));
typedef unsigned short ushort_t;

constexpr int B  = 1024;
constexpr int M  = 65536;
constexpr int D  = 384;
constexpr int H  = 384;
constexpr int KK = 5;
constexpr int NC = 128;         // chunks over M
constexpr int CHUNK = M / NC;   // 512 mems per chunk
constexpr float FEPS = 1e-8f;

__device__ __forceinline__ ushort_t f2bf(float x) {
  unsigned int u = __float_as_uint(x);
  unsigned int r = (u + 0x7FFFu + ((u >> 16) & 1u)) >> 16;   // RNE
  return (ushort_t)r;
}
__device__ __forceinline__ float bf2f(ushort_t h) {
  return __uint_as_float(((unsigned int)h) << 16);
}

__device__ __forceinline__ void async16(const ushort_t* g, ushort_t* l) {
  __builtin_amdgcn_global_load_lds(
      (const __attribute__((address_space(1))) unsigned int*)g,
      (__attribute__((address_space(3))) unsigned int*)l, 16, 0, 0);
}

__device__ __forceinline__ void insert3b(unsigned int* k, unsigned int v) {
  unsigned int t0 = min(k[0], v); k[0] = max(k[0], v);
  unsigned int t1 = min(k[1], t0); k[1] = max(k[1], t0);
  k[2] = max(k[2], t1);
}
__device__ __forceinline__ void insert5b(unsigned int* k, unsigned int v) {
  unsigned int t0 = min(k[0], v); k[0] = max(k[0], v);
  unsigned int t1 = min(k[1], t0); k[1] = max(k[1], t0);
  unsigned int t2 = min(k[2], t1); k[2] = max(k[2], t1);
  unsigned int t3 = min(k[3], t2); k[3] = max(k[3], t2);
  k[4] = max(k[4], t3);
}

// swizzled per-lane global k-offset for staging: LDS granule (lane&3) of row
// (lane>>2) holds logical granule (lane&3) ^ ((row>>1)&3).  [bank-conflict fix]
__device__ __forceinline__ int swz_koff(int lane) {
  return (((lane & 3) ^ ((lane >> 3) & 3)) * 8);
}

// ======= prep: mem hi-split+stats | q norm-hi | weight hi/lo splits =========
// float4 (16B/lane) streaming: each wave handles a ROW PAIR (2x1536B = exactly
// 3x64 float4), masked dual norm accumulators (k=0 -> row0, k=2 -> row1,
// k=1 splits at lane 32), ushort4 bf16 stores. Guideline 13.
__global__ __launch_bounds__(256) void k_prep(
    const float* __restrict__ q, const float* __restrict__ mem,
    const float* __restrict__ coords, const float* __restrict__ sw,
    const float* __restrict__ W_ih, const float* __restrict__ W_hh,
    const float* __restrict__ W_g,
    ushort_t* __restrict__ qh, ushort_t* __restrict__ mh,
    float2* __restrict__ f2a, float2* __restrict__ f2b,
    ushort_t* __restrict__ wihh, ushort_t* __restrict__ wihl,
    ushort_t* __restrict__ whhh, ushort_t* __restrict__ whhl,
    ushort_t* __restrict__ wgh, ushort_t* __restrict__ wgl) {
  int wv = threadIdx.x >> 6, lane = threadIdx.x & 63;
  int bid = blockIdx.x;
  if (bid < M/8) {
    int r0 = bid*8 + wv*2;
    float cx = 0.f, cy = 0.f;
    for (int i = lane; i < H; i += 64) { cx += sw[2*i]; cy += sw[2*i+1]; }
#pragma unroll
    for (int o = 32; o > 0; o >>= 1) { cx += __shfl_xor(cx, o); cy += __shfl_xor(cy, o); }
    cx *= (1.0f/384.0f); cy *= (1.0f/384.0f);
    float4 x[3]; float s0 = 0.f, s1 = 0.f;
#pragma unroll
    for (int k = 0; k < 3; ++k) {
      x[k] = ((const float4*)(mem + (size_t)r0*D))[lane + 64*k];
      float d = x[k].x*x[k].x + x[k].y*x[k].y + x[k].z*x[k].z + x[k].w*x[k].w;
      if (k == 0) s0 += d;
      else if (k == 2) s1 += d;
      else { if (lane < 32) s0 += d; else s1 += d; }
    }
#pragma unroll
    for (int o = 32; o > 0; o >>= 1) { s0 += __shfl_xor(s0, o); s1 += __shfl_xor(s1, o); }
#pragma unroll
    for (int k = 0; k < 3; ++k) {
      ushort4 hh;
      hh.x = f2bf(x[k].x); hh.y = f2bf(x[k].y);
      hh.z = f2bf(x[k].z); hh.w = f2bf(x[k].w);
      ((ushort4*)(mh + (size_t)r0*D))[lane + 64*k] = hh;
    }
    if (lane < 2) {
      int r = r0 + lane;
      float mn = sqrtf(lane == 0 ? s0 : s1);
      float dx = coords[2*r] - cx, dy = coords[2*r+1] - cy;
      float act = 1.0f / (1.0f + sqrtf(dx*dx + dy*dy));
      f2a[r] = make_float2(1.0f / mn, act + 2.0f);
      f2b[r] = make_float2(mn, act);
    }
  } else if (bid < M/8 + B/8) {
    int r0 = (bid - M/8)*8 + wv*2;
    float4 x[3]; float s0 = 0.f, s1 = 0.f;
#pragma unroll
    for (int k = 0; k < 3; ++k) {
      x[k] = ((const float4*)(q + (size_t)r0*D))[lane + 64*k];
      float d = x[k].x*x[k].x + x[k].y*x[k].y + x[k].z*x[k].z + x[k].w*x[k].w;
      if (k == 0) s0 += d;
      else if (k == 2) s1 += d;
      else { if (lane < 32) s0 += d; else s1 += d; }
    }
#pragma unroll
    for (int o = 32; o > 0; o >>= 1) { s0 += __shfl_xor(s0, o); s1 += __shfl_xor(s1, o); }
    float inv0 = 1.0f / sqrtf(s0), inv1 = 1.0f / sqrtf(s1);
#pragma unroll
    for (int k = 0; k < 3; ++k) {
      float sc = (k == 0) ? inv0 : (k == 2) ? inv1 : (lane < 32 ? inv0 : inv1);
      ushort4 nn;
      nn.x = f2bf(x[k].x * sc); nn.y = f2bf(x[k].y * sc);
      nn.z = f2bf(x[k].z * sc); nn.w = f2bf(x[k].w * sc);
      ((ushort4*)(qh + (size_t)r0*D))[lane + 64*k] = nn;
    }
  } else {
    int r = (bid - M/8 - B/8)*4 + wv;   // 0..1151
    const float* src; ushort_t* dh; ushort_t* dl;
    if (r < 384)      { src = W_ih + (size_t)r*D;       dh = wihh + (size_t)r*D;       dl = wihl + (size_t)r*D; }
    else if (r < 768) { src = W_hh + (size_t)(r-384)*D; dh = whhh + (size_t)(r-384)*D; dl = whhl + (size_t)(r-384)*D; }
    else              { src = W_g  + (size_t)(r-768)*D; dh = wgh  + (size_t)(r-768)*D; dl = wgl  + (size_t)(r-768)*D; }
#pragma unroll
    for (int k = 0; k < 3; ++k) {
      float2 v = ((const float2*)src)[lane + 64*k];
      ushort_t h0 = f2bf(v.x), h1 = f2bf(v.y);
      ushort2 hh; hh.x = h0; hh.y = h1;
      ushort2 ll; ll.x = f2bf(v.x - bf2f(h0)); ll.y = f2bf(v.y - bf2f(h1));
      ((ushort2*)dh)[lane + 64*k] = hh;
      ((ushort2*)dl)[lane + 64*k] = ll;
    }
  }
}

// ====== sim: 1-term mh x qh 32x32x16 MFMA, BK=64, double-buffered 2-phase ===
// 1D grid 1024; XCD-aware decode: the 8 q-tiles sharing chunk nc are
// consecutive on XCD nc%8 -> chunk read from HBM once, L2-hit 7x.
__global__ __launch_bounds__(256, 2) void k_sim(
    const ushort_t* __restrict__ qh,
    const ushort_t* __restrict__ mh,
    const float2* __restrict__ f2a, unsigned int* __restrict__ keybuf) {
  __shared__ __align__(16) ushort_t sQh[2*8192];   // [buf][kb*4096+slot*512+lane*8]
  __shared__ __align__(16) ushort_t sMh[2*8192];
  __shared__ __align__(16) float2 sF[CHUNK];   // per-chunk (1/mn, act+2)

  const int tid = threadIdx.x, lane = tid & 63, wave = tid >> 6;
  const int wr = wave >> 1, wc = wave & 1;
  const int l31 = lane & 31, half = lane >> 5;
  const int flat = blockIdx.x;
  const int k8 = flat & 7, qb = (flat >> 3) & 7, mgrp = flat >> 6;
  const int nc = (mgrp << 3) | k8;
  const int rowoff = lane >> 2, koff = swz_koff(lane);
  const int gsw = (l31 >> 1) & 3;          // read-side swizzle
  const size_t qrow0 = (size_t)qb * 128;

  // stage chunk stats once (coalesced): 256 x float4 = 512 float2
  ((float4*)sF)[tid] = ((const float4*)(f2a + (size_t)nc * CHUNK))[tid];

  // per-wave slot decode for staging (same addressing as before)
  auto stage = [&](int buf, int mt, int k6) {
    const size_t mrow0 = (size_t)nc * CHUNK + (size_t)mt * 128;
    const int kt = k6 * 64;
#pragma unroll
    for (int n = 0; n < 8; ++n) {
      int f = wave*8 + n;
      int arr = f >> 4, sub = f & 15, kb = sub >> 3, slot = sub & 7;
      const ushort_t* src = arr == 0 ? qh : mh;
      ushort_t* dst = (arr == 0 ? sQh : sMh) + buf*8192;
      size_t rowb = arr == 0 ? qrow0 : mrow0;
      async16(src + (rowb + slot*16 + rowoff)*D + kt + kb*32 + koff,
              dst + kb*4096 + slot*512 + lane*8);
    }
  };

  unsigned int keys[2][3];
#pragma unroll
  for (int j = 0; j < 2; ++j) { keys[j][0] = 0; keys[j][1] = 0; keys[j][2] = 0; }

  // prologue: stage (mt=0,k6=0) into buf 0, drain
  stage(0, 0, 0);
  __syncthreads();

  int cur = 0;
  f32x16 acc[2][2];

  for (int mt = 0; mt < 4; ++mt) {
#pragma unroll
    for (int i = 0; i < 2; ++i)
#pragma unroll
      for (int j = 0; j < 2; ++j) acc[i][j] = (f32x16)0.0f;

#pragma unroll
    for (int k6 = 0; k6 < 6; ++k6) {
      // issue next tile's loads first (overlap with compute below)
      const int nmt = (k6 == 5) ? mt + 1 : mt;
      const int nk6 = (k6 == 5) ? 0 : k6 + 1;
      if (nmt < 4) stage(cur ^ 1, nmt, nk6);

      // compute on buf 'cur'
      const int bufo = cur * 8192;
#pragma unroll
      for (int kb = 0; kb < 2; ++kb) {
        const int base = bufo + kb*4096;
        bf16x8 ah[2][2], bh[2][2];
#pragma unroll
        for (int i = 0; i < 2; ++i)
#pragma unroll
          for (int s = 0; s < 2; ++s) {
            int gra = ((s*2 + half) ^ gsw) * 8;
            int ro = base + (wr*64 + i*32 + l31)*32 + gra;
            ah[i][s] = *(const bf16x8*)&sMh[ro];
            int co = base + (wc*64 + i*32 + l31)*32 + gra;
            bh[i][s] = *(const bf16x8*)&sQh[co];
          }
#pragma unroll
        for (int i = 0; i < 2; ++i)
#pragma unroll
          for (int j = 0; j < 2; ++j)
#pragma unroll
            for (int s = 0; s < 2; ++s)
              acc[i][j] = __builtin_amdgcn_mfma_f32_32x32x16_bf16(ah[i][s], bh[j][s], acc[i][j], 0, 0, 0);
      }

      // epilogue for this mt overlaps the in-flight next-tile loads
      if (k6 == 5) {
#pragma unroll
        for (int i = 0; i < 2; ++i)
#pragma unroll
          for (int rg = 0; rg < 4; ++rg)
#pragma unroll
            for (int rr = 0; rr < 4; ++rr) {
              int rl = wr*64 + i*32 + half*4 + rr + 8*rg;
              float2 fa = sF[mt*128 + rl];
              unsigned int idx = (unsigned int)(((nc & 1) << 9) | (mt*128 + rl));
              float v0 = fmaf(acc[i][0][rg*4+rr], fa.x, fa.y);
              insert3b(keys[0], (__float_as_uint(v0) & 0xFFFFFC00u) | idx);
              float v1 = fmaf(acc[i][1][rg*4+rr], fa.x, fa.y);
              insert3b(keys[1], (__float_as_uint(v1) & 0xFFFFFC00u) | idx);
            }
      }

      // single barrier per step: drains vmcnt(0) for the loads issued above
      __syncthreads();
      cur ^= 1;
    }
  }

#pragma unroll
  for (int j = 0; j < 2; ++j) {
    int q_local = wc*64 + j*32 + l31;
    int c = wr*2 + half;
    size_t off = ((size_t)(qb*128 + q_local) * NC + nc) * 12 + c*3;
    keybuf[off+0] = keys[j][0];
    keybuf[off+1] = keys[j][1];
    keybuf[off+2] = keys[j][2];
  }
}

// == merge: block/query; tournament + exact rescore + fused seq gather-split ==
__global__ __launch_bounds__(256) void k_merge(
    const unsigned int* __restrict__ keybuf,
    const float* __restrict__ query, const float* __restrict__ memv,
    const float2* __restrict__ f2b,
    ushort_t* __restrict__ xsh, ushort_t* __restrict__ xsl) {
  __shared__ int sCand[16];
  __shared__ float sSimv[16];
  __shared__ int sTop[KK];
  const int tid = threadIdx.x, lane = tid & 63, wave = tid >> 6;
  const int q = blockIdx.x;

  if (wave == 0) {
    // lane covers chunks 2*lane, 2*lane+1: 24 contiguous keys
    const unsigned int* kb = keybuf + (size_t)q * (NC*12) + (size_t)lane * 24;
    unsigned int k5[5] = {0,0,0,0,0};
#pragma unroll
    for (int c = 0; c < 6; ++c) {
      uint4 v = *(const uint4*)(kb + c*4);
      insert5b(k5, v.x); insert5b(k5, v.y); insert5b(k5, v.z); insert5b(k5, v.w);
    }
#pragma unroll
    for (int p = 0; p < 16; ++p) {
      unsigned int bk = k5[0]; int blv = lane;
#pragma unroll
      for (int off = 1; off < 64; off <<= 1) {
        unsigned int ok = (unsigned int)__shfl_xor((int)bk, off);
        int ol = __shfl_xor(blv, off);
        if (ok > bk || (ok == bk && ol < blv)) { bk = ok; blv = ol; }
      }
      if (lane == blv) { k5[0]=k5[1]; k5[1]=k5[2]; k5[2]=k5[3]; k5[3]=k5[4]; k5[4]=0; }
      if (lane == 0) sCand[p] = (blv << 10) | (int)(bk & 1023u);
    }
  }
  __syncthreads();

  // each wave rescores 4 candidates in exact fp32
  float qv[6]; float sq = 0.f;
#pragma unroll
  for (int k = 0; k < 6; ++k) { qv[k] = query[(size_t)q*D + lane + 64*k]; sq += qv[k]*qv[k]; }
#pragma unroll
  for (int o = 32; o > 0; o >>= 1) sq += __shfl_xor(sq, o);
  float qn = sqrtf(sq);

#pragma unroll
  for (int pp = 0; pp < 4; ++pp) {
    int p = wave*4 + pp;
    int mi = sCand[p];
    float d = 0.f;
#pragma unroll
    for (int k = 0; k < 6; ++k) d += qv[k] * memv[(size_t)mi*D + lane + 64*k];
#pragma unroll
    for (int o = 32; o > 0; o >>= 1) d += __shfl_xor(d, o);
    if (lane == 0) {
      float2 fb = f2b[mi];
      sSimv[p] = d / fmaxf(qn * fb.x, FEPS) + fb.y;
    }
  }
  __syncthreads();

  if (tid == 0) {
    float cv[16]; int ci[16];
#pragma unroll
    for (int p = 0; p < 16; ++p) { cv[p] = sSimv[p]; ci[p] = sCand[p]; }
    for (int s = 0; s < KK; ++s) {
      int best = -1; float bv = -1e30f; int bi = 0x7FFFFFFF;
      for (int p = 0; p < 16; ++p) {
        if (ci[p] < 0) continue;
        if (cv[p] > bv || (cv[p] == bv && ci[p] < bi)) { best = p; bv = cv[p]; bi = ci[p]; }
      }
      sTop[s] = ci[best];
      ci[best] = -1;
    }
  }
  __syncthreads();

  // fused seq gather + hi/lo split: rows g = q*6 + t (t=0 query, t>0 retrieved)
#pragma unroll
  for (int rep = 0; rep < 2; ++rep) {
    int t = wave + rep*4;
    if (t < 6) {
      const float* src = (t == 0) ? (query + (size_t)q*D)
                                  : (memv + (size_t)sTop[t-1]*D);
      size_t g = (size_t)q*6 + t;
#pragma unroll
      for (int k = 0; k < 3; ++k) {
        float2 v = ((const float2*)src)[lane + 64*k];
        ushort_t h0 = f2bf(v.x), h1 = f2bf(v.y);
        ushort2 hh; hh.x = h0; hh.y = h1;
        ushort2 ll; ll.x = f2bf(v.x - bf2f(h0)); ll.y = f2bf(v.y - bf2f(h1));
        ((ushort2*)(xsh + g*D))[lane + 64*k] = hh;
        ((ushort2*)(xsl + g*D))[lane + 64*k] = ll;
      }
    }
  }
}

// ===== tail1: x_proj (contiguous seq rows, 96 tiles) + gate (16 tiles) + h1 =
// grid (112, 6); 64x64 tile, K=384 in 3 rounds of 4x32 subtiles; 3-term split
__global__ __launch_bounds__(256) void k_tail1(
    const ushort_t* __restrict__ xsh, const ushort_t* __restrict__ xsl,
    const ushort_t* __restrict__ wihh, const ushort_t* __restrict__ wihl,
    const ushort_t* __restrict__ wgh, const ushort_t* __restrict__ wgl,
    const float* __restrict__ b_ih, const float* __restrict__ b_hh,
    const float* __restrict__ b_g,
    float* __restrict__ xp, float* __restrict__ gate,
    ushort_t* __restrict__ hoh, ushort_t* __restrict__ hol) {
  __shared__ __align__(16) ushort_t sAh[64*128];
  __shared__ __align__(16) ushort_t sAl[64*128];
  __shared__ __align__(16) ushort_t sWh[64*128];
  __shared__ __align__(16) ushort_t sWl[64*128];

  const int tid = threadIdx.x, lane = tid & 63, wave = tid >> 6;
  const int wr = wave >> 1, wc = wave & 1;
  const int t = lane & 15, quad = lane >> 4;
  const bool xmode = blockIdx.x < 96;
  const int cbase = blockIdx.y * 64;
  const int rowoff = lane >> 2, koff = swz_koff(lane);
  const int pq = (quad ^ ((t >> 1) & 3)) * 8;    // swizzled read granule

  const ushort_t* gp[4];
  if (wave < 2) {
    const ushort_t* base = (wave == 0) ? xsh : xsl;
#pragma unroll
    for (int slot = 0; slot < 4; ++slot) {
      int rl = slot*16 + rowoff;
      size_t row = xmode ? (size_t)(blockIdx.x*64 + rl)
                         : (size_t)((blockIdx.x - 96)*64 + rl) * 6;
      gp[slot] = base + row*D + koff;
    }
  } else {
#pragma unroll
    for (int slot = 0; slot < 4; ++slot) {
      int rl = slot*16 + rowoff;
      const ushort_t* wsrc = xmode ? (wave == 2 ? wihh : wihl)
                                   : (wave == 2 ? wgh  : wgl);
      gp[slot] = wsrc + (size_t)(cbase + rl) * D + koff;
    }
  }
  ushort_t* ldst = (wave == 0) ? sAh : (wave == 1) ? sAl : (wave == 2) ? sWh : sWl;

  f32x4 acc[2][2];
#pragma unroll
  for (int i = 0; i < 2; ++i)
#pragma unroll
    for (int j = 0; j < 2; ++j) acc[i][j] = (f32x4)0.0f;

  for (int r3 = 0; r3 < 3; ++r3) {
    __syncthreads();
#pragma unroll
    for (int s = 0; s < 4; ++s)
#pragma unroll
      for (int slot = 0; slot < 4; ++slot)
        async16(gp[slot] + r3*128 + s*32, ldst + s*2048 + slot*512 + lane*8);
    __syncthreads();
#pragma unroll
    for (int s = 0; s < 4; ++s) {
      bf16x8 ah[2], al[2], bh[2], bl[2];
#pragma unroll
      for (int i = 0; i < 2; ++i) {
        int ro = s*2048 + (wr*32 + i*16 + t)*32 + pq;
        ah[i] = *(const bf16x8*)&sAh[ro];
        al[i] = *(const bf16x8*)&sAl[ro];
        int co = s*2048 + (wc*32 + i*16 + t)*32 + pq;
        bh[i] = *(const bf16x8*)&sWh[co];
        bl[i] = *(const bf16x8*)&sWl[co];
      }
#pragma unroll
      for (int i = 0; i < 2; ++i)
#pragma unroll
        for (int j = 0; j < 2; ++j) {
          acc[i][j] = __builtin_amdgcn_mfma_f32_16x16x32_bf16(ah[i], bh[j], acc[i][j], 0, 0, 0);
          acc[i][j] = __builtin_amdgcn_mfma_f32_16x16x32_bf16(ah[i], bl[j], acc[i][j], 0, 0, 0);
          acc[i][j] = __builtin_amdgcn_mfma_f32_16x16x32_bf16(al[i], bh[j], acc[i][j], 0, 0, 0);
        }
    }
  }

#pragma unroll
  for (int i = 0; i < 2; ++i)
#pragma unroll
    for (int j = 0; j < 2; ++j)
#pragma unroll
      for (int r = 0; r < 4; ++r) {
        int rloc = wr*32 + i*16 + quad*4 + r;
        int h = cbase + wc*32 + j*16 + t;
        float a = acc[i][j][r];
        if (xmode) {
          int g = blockIdx.x*64 + rloc;
          float v = a + b_ih[h];
          xp[(size_t)g*H + h] = v;
          int b = g / 6;
          if (g - b*6 == 0) {
            float hv = tanhf(v + b_hh[h]);
            ushort_t hi = f2bf(hv);
            hoh[(size_t)b*H + h] = hi;
            hol[(size_t)b*H + h] = f2bf(hv - bf2f(hi));
          }
        } else {
          int rq = (blockIdx.x - 96)*64 + rloc;
          gate[(size_t)rq*H + h] = 1.0f / (1.0f + expf(-(a + b_g[h])));
        }
      }
}

// ========= RNN step: h' = tanh(x_t + h @ W_hh^T + b_hh), 32x64 tiles =======
// grid (32, 6) = 192 blocks (75% CU util). Same 2-barrier schedule and
// identical per-element math order as the verified 64x64 k_rnn.
template<int LAST>
__global__ __launch_bounds__(256) void k_rnn(
    const ushort_t* __restrict__ hih, const ushort_t* __restrict__ hil,
    const ushort_t* __restrict__ whhh, const ushort_t* __restrict__ whhl,
    const float* __restrict__ b_hh, const float* __restrict__ xp,
    const float* __restrict__ gate, int step,
    ushort_t* __restrict__ hoh, ushort_t* __restrict__ hol,
    float* __restrict__ out) {
  __shared__ __align__(16) ushort_t sAh[32*128];
  __shared__ __align__(16) ushort_t sAl[32*128];
  __shared__ __align__(16) ushort_t sWh[64*128];
  __shared__ __align__(16) ushort_t sWl[64*128];

  const int tid = threadIdx.x, lane = tid & 63, wave = tid >> 6;
  const int wr = wave >> 1, wc = wave & 1;
  const int t = lane & 15, quad = lane >> 4;
  const int rbase = blockIdx.x * 32, cbase = blockIdx.y * 64;
  const int rowoff = lane >> 2, koff = swz_koff(lane);
  const int pq = (quad ^ ((t >> 1) & 3)) * 8;
  const int nslot = (wave < 2) ? 2 : 4;           // A: 32 rows, W: 64 cols
  const int sstride = (wave < 2) ? 1024 : 2048;   // LDS subtile stride (ushorts)

  const ushort_t* gp[4];
#pragma unroll
  for (int slot = 0; slot < 4; ++slot) {
    int rl = slot*16 + rowoff;
    const ushort_t* src =
        (wave == 0) ? hih + (size_t)(rbase + rl)*D :
        (wave == 1) ? hil + (size_t)(rbase + rl)*D :
        (wave == 2) ? whhh + (size_t)(cbase + rl)*D :
                      whhl + (size_t)(cbase + rl)*D;
    gp[slot] = src + koff;
  }
  ushort_t* ldst = (wave == 0) ? sAh : (wave == 1) ? sAl : (wave == 2) ? sWh : sWl;

  f32x4 acc[2];
#pragma unroll
  for (int j = 0; j < 2; ++j) acc[j] = (f32x4)0.0f;

  for (int r3 = 0; r3 < 3; ++r3) {
    __syncthreads();
#pragma unroll
    for (int s = 0; s < 4; ++s)
      for (int slot = 0; slot < nslot; ++slot)
        async16(gp[slot] + r3*128 + s*32, ldst + s*sstride + slot*512 + lane*8);
    __syncthreads();
#pragma unroll
    for (int s = 0; s < 4; ++s) {
      int ro = s*1024 + (wr*16 + t)*32 + pq;
      bf16x8 ah = *(const bf16x8*)&sAh[ro];
      bf16x8 al = *(const bf16x8*)&sAl[ro];
      bf16x8 bh[2], bl[2];
#pragma unroll
      for (int j = 0; j < 2; ++j) {
        int co = s*2048 + (wc*32 + j*16 + t)*32 + pq;
        bh[j] = *(const bf16x8*)&sWh[co];
        bl[j] = *(const bf16x8*)&sWl[co];
      }
#pragma unroll
      for (int j = 0; j < 2; ++j) {
        acc[j] = __builtin_amdgcn_mfma_f32_16x16x32_bf16(ah, bh[j], acc[j], 0, 0, 0);
        acc[j] = __builtin_amdgcn_mfma_f32_16x16x32_bf16(ah, bl[j], acc[j], 0, 0, 0);
        acc[j] = __builtin_amdgcn_mfma_f32_16x16x32_bf16(al, bh[j], acc[j], 0, 0, 0);
      }
    }
  }

#pragma unroll
  for (int j = 0; j < 2; ++j)
#pragma unroll
    for (int r = 0; r < 4; ++r) {
      int row = rbase + wr*16 + quad*4 + r;
      int h = cbase + wc*32 + j*16 + t;
      float v = acc[j][r] + b_hh[h] + xp[(size_t)row*(6*H) + step*H + h];
      float hv = tanhf(v);
      if (LAST) {
        float g = gate[(size_t)row*H + h];
        out[(size_t)row*H + h] = g*hv + (1.0f - g)*xp[(size_t)row*(6*H) + h];
      } else {
        ushort_t hi = f2bf(hv);
        hoh[(size_t)row*H + h] = hi;
        hol[(size_t)row*H + h] = f2bf(hv - bf2f(hi));
      }
    }
}

} // namespace

extern "C" void kernel_launch(void* const* d_in, const int* in_sizes, int n_in,
                              void* d_out, int out_size, void* d_ws, size_t ws_size,
                              hipStream_t stream) {
  const float* query = (const float*)d_in[0];
  const float* memv  = (const float*)d_in[1];
  const float* coords= (const float*)d_in[2];
  const float* sw    = (const float*)d_in[3];
  const float* W_ih  = (const float*)d_in[4];
  const float* b_ih  = (const float*)d_in[5];
  const float* W_hh  = (const float*)d_in[6];
  const float* b_hh  = (const float*)d_in[7];
  const float* W_g   = (const float*)d_in[8];
  const float* b_g   = (const float*)d_in[9];
  float* out = (float*)d_out;

  char* p = (char*)d_ws;
  auto alloc = [&](size_t bytes) {
    char* r = p; p += (bytes + 255) & ~(size_t)255; return r;
  };
  ushort_t* qh  = (ushort_t*)alloc((size_t)B * D * 2);
  ushort_t* mh  = (ushort_t*)alloc((size_t)M * D * 2);
  float2* f2a   = (float2*)alloc((size_t)M * 8);
  float2* f2b   = (float2*)alloc((size_t)M * 8);
  ushort_t* wihh = (ushort_t*)alloc((size_t)H * D * 2);
  ushort_t* wihl = (ushort_t*)alloc((size_t)H * D * 2);
  ushort_t* whhh = (ushort_t*)alloc((size_t)H * D * 2);
  ushort_t* whhl = (ushort_t*)alloc((size_t)H * D * 2);
  ushort_t* wgh  = (ushort_t*)alloc((size_t)H * D * 2);
  ushort_t* wgl  = (ushort_t*)alloc((size_t)H * D * 2);
  unsigned int* keybuf = (unsigned int*)alloc((size_t)B * NC * 12 * 4);
  ushort_t* xsh = (ushort_t*)alloc((size_t)B * 6 * D * 2);
  ushort_t* xsl = (ushort_t*)alloc((size_t)B * 6 * D * 2);
  float* xp     = (float*)alloc((size_t)B * 6 * H * 4);
  float* gate   = (float*)alloc((size_t)B * H * 4);
  ushort_t* hAh = (ushort_t*)alloc((size_t)B * H * 2);
  ushort_t* hAl = (ushort_t*)alloc((size_t)B * H * 2);
  ushort_t* hBh = (ushort_t*)alloc((size_t)B * H * 2);
  ushort_t* hBl = (ushort_t*)alloc((size_t)B * H * 2);

  k_prep<<<M/8 + B/8 + 288, 256, 0, stream>>>(
      query, memv, coords, sw, W_ih, W_hh, W_g,
      qh, mh, f2a, f2b,
      wihh, wihl, whhh, whhl, wgh, wgl);
  k_sim<<<1024, 256, 0, stream>>>(qh, mh, f2a, keybuf);
  k_merge<<<B, 256, 0, stream>>>(keybuf, query, memv, f2b, xsh, xsl);
  k_tail1<<<dim3(112, 6), 256, 0, stream>>>(
      xsh, xsl, wihh, wihl, wgh, wgl,
      b_ih, b_hh, b_g, xp, gate, hAh, hAl);
  k_rnn<0><<<dim3(32, 6), 256, 0, stream>>>(hAh, hAl, whhh, whhl, b_hh, xp, gate, 1, hBh, hBl, out);
  k_rnn<0><<<dim3(32, 6), 256, 0, stream>>>(hBh, hBl, whhh, whhl, b_hh, xp, gate, 2, hAh, hAl, out);
  k_rnn<0><<<dim3(32, 6), 256, 0, stream>>>(hAh, hAl, whhh, whhl, b_hh, xp, gate, 3, hBh, hBl, out);
  k_rnn<0><<<dim3(32, 6), 256, 0, stream>>>(hBh, hBl, whhh, whhl, b_hh, xp, gate, 4, hAh, hAl, out);
  k_rnn<1><<<dim3(32, 6), 256, 0, stream>>>(hAh, hAl, whhh, whhl, b_hh, xp, gate, 5, hBh, hBl, out);
}